// Round 14
// baseline (207.216 us; speedup 1.0000x reference)
//
#include <hip/hip_runtime.h>
#include <math.h>

// Problem constants
#define BB   32
#define HN   12
#define N1   256
#define N2   320
#define SS   256
#define BH   (BB*HN)                 // 384
#define R4   (N2/4)                  // 80 float4 per row
#define SLICE4 ((size_t)N1*R4)       // f4 per (b,h) per tensor = 20480

typedef float v4f __attribute__((ext_vector_type(4)));

// One block of 1024 threads (16 waves) per (b,h). No inter-block sync, no
// workspace. launch_bounds(1024,8) -> VGPR<=64 -> 2 blocks/CU -> heavy CUs
// run 32 waves (full occupancy) for maximum outstanding-load depth.
//  Phase A: read own slice, 512 row-maxes -> LDS.
//  Phase B: scatter -> LN(512) -> GEMM1(relu) -> GEMM2(sigmoid) (thr<512).
//  Phase C: re-read own slice (MALL-hot), scale, NT-store.
__global__ __launch_bounds__(1024, 8) void k_fused(
    const float* __restrict__ rgb, const float* __restrict__ tir,
    const int*   __restrict__ gidx,
    const float* __restrict__ ln_g, const float* __restrict__ ln_b,
    const float* __restrict__ W1,  const float* __restrict__ b1,
    const float* __restrict__ W2,  const float* __restrict__ b2,
    v4f* __restrict__ outTir, v4f* __restrict__ outRgb)
{
    __shared__ float mxs[2 * SS];    // row maxes: rgb [0,256), tir [256,512)
    __shared__ float v[2 * SS];      // scattered -> normalized vector
    __shared__ float hs[SS];         // hidden relu
    __shared__ float gs[2 * SS];     // sigmoid gates
    __shared__ float growR[SS];      // per-row gate, rgb
    __shared__ float growT[SS];      // per-row gate, tir
    __shared__ int   sidx_s[SS];
    __shared__ float red[32];

    const int bh   = (int)blockIdx.x;    // 0..383
    const int b    = bh / HN;
    const int t    = (int)threadIdx.x;   // 0..1023
    const int w    = t >> 6;             // wave 0..15
    const int lane = t & 63;

    if (t < SS) sidx_s[t] = gidx[b * SS + t];
    if (t < 2 * SS) v[t] = 0.f;

    const float* sliceR = rgb + (size_t)bh * (N1 * N2);
    const float* sliceT = tir + (size_t)bh * (N1 * N2);

    // ---- Phase A: 512 row-units (tensor*256+row); wave w owns 32; 8-deep --
    for (int uu = 0; uu < 32; uu += 8) {
        const int u0 = w * 32 + uu;
        v4f a[8], b8[8];
#pragma unroll
        for (int q = 0; q < 8; ++q) {
            int u = u0 + q;
            const v4f* p = (const v4f*)((u >= SS ? sliceT : sliceR)
                                        + (size_t)(u & 255) * N2);
            a[q]  = p[lane];
            // tail f4s [64,80): lane-duplicated (no effect on max; duplicate
            // addresses coalesce to the same cache lines)
            b8[q] = p[64 + (lane & 15)];
        }
#pragma unroll
        for (int q = 0; q < 8; ++q) {
            float m = fmaxf(fmaxf(fmaxf(a[q].x, a[q].y), fmaxf(a[q].z, a[q].w)),
                            fmaxf(fmaxf(b8[q].x, b8[q].y), fmaxf(b8[q].z, b8[q].w)));
#pragma unroll
            for (int off = 32; off; off >>= 1) m = fmaxf(m, __shfl_xor(m, off));
            if (lane == 0) mxs[u0 + q] = m;
        }
    }
    __syncthreads();

    // ---- Phase B1: scatter (per-batch permutation -> collision-free) ----
    if (t < SS) {
        int sidx = sidx_s[t];
        v[sidx]      = mxs[t];
        v[sidx + SS] = mxs[t + SS];
    }
    __syncthreads();

    // ---- Phase B2: LayerNorm over 512 (threads 0..511; others add zeros) --
    {
        float x = (t < 2 * SS) ? v[t] : 0.f;
        float s  = x;
        float sq = x * x;
#pragma unroll
        for (int off = 32; off; off >>= 1) {
            s  += __shfl_xor(s, off);
            sq += __shfl_xor(sq, off);
        }
        if (lane == 0) { red[w] = s; red[16 + w] = sq; }
        __syncthreads();
        s = 0.f; sq = 0.f;
#pragma unroll
        for (int k = 0; k < 8; ++k) { s += red[k]; sq += red[16 + k]; }
        const float mu   = s * (1.f / 512.f);
        const float var  = sq * (1.f / 512.f) - mu * mu;
        const float rstd = rsqrtf(var + 1e-5f);
        if (t < 2 * SS) v[t] = (x - mu) * rstd * ln_g[t] + ln_b[t];
    }
    __syncthreads();

    // ---- Phase B3: GEMM1 (threads 0..511, R10 structure) ----
    if (t < 2 * SS) {
        float a0 = b1[t & 255], a1 = 0.f;
        const int out = t & 255, seg = t >> 8;     // seg 0/1 -> K halves
        const int e0  = seg * SS;
#pragma unroll 8
        for (int e = 0; e < 128; ++e)
            a0 = fmaf(v[e0 + e],       W1[(size_t)(e0 + e) * SS + out], a0);
#pragma unroll 8
        for (int e = 128; e < 256; ++e)
            a1 = fmaf(v[e0 + e],       W1[(size_t)(e0 + e) * SS + out], a1);
        // two partials per output (seg 0 adds bias); combine via LDS
        gs[t] = a0 + a1 - ((seg == 1) ? b1[out] : 0.f) * 0.f;  // gs reused as scratch
        // note: seg0 partial includes bias, seg1 partial raw
    }
    __syncthreads();
    if (t < SS) hs[t] = fmaxf(gs[t] + gs[t + SS], 0.f);
    __syncthreads();

    // ---- Phase B4: GEMM2 (threads 0..511, one output each) ----
    if (t < 2 * SS) {
        float a0 = b2[t], a1 = 0.f;
#pragma unroll 8
        for (int f = 0; f < 128; ++f)      a0 = fmaf(hs[f], W2[(size_t)f * (2 * SS) + t], a0);
#pragma unroll 8
        for (int f = 128; f < 256; ++f)    a1 = fmaf(hs[f], W2[(size_t)f * (2 * SS) + t], a1);
        gs[t] = 1.f / (1.f + expf(-(a0 + a1)));
    }
    __syncthreads();

    // ---- Phase B5: gather per-row gates ----
    if (t < SS) {
        growR[t] = gs[sidx_s[t]];
        growT[t] = gs[sidx_s[t] + SS];
    }
    __syncthreads();

    // ---- Phase C: hot re-read own slice, scale, NT-store ----
    // 40960 f4 (both tensors), flat: i = k*1024 + t; tir first half.
    {
        const v4f* srcR4 = (const v4f*)sliceR;
        const v4f* srcT4 = (const v4f*)sliceT;
        v4f* dstR = outRgb + (size_t)bh * SLICE4;
        v4f* dstT = outTir + (size_t)bh * SLICE4;
        for (int k = 0; k < 40; k += 8) {
            v4f a[8]; float g[8];
#pragma unroll
            for (int q = 0; q < 8; ++q) {
                unsigned i = (unsigned)(k + q) * 1024u + (unsigned)t;  // < 40960
                int isRgb  = i >= 20480u;
                unsigned j = isRgb ? i - 20480u : i;
                a[q] = isRgb ? srcR4[j] : srcT4[j];
                g[q] = (isRgb ? growR : growT)[j / 80u];
            }
#pragma unroll
            for (int q = 0; q < 8; ++q) {
                unsigned i = (unsigned)(k + q) * 1024u + (unsigned)t;
                int isRgb  = i >= 20480u;
                unsigned j = isRgb ? i - 20480u : i;
                __builtin_nontemporal_store(a[q] * g[q],
                                            (isRgb ? dstR : dstT) + j);
            }
        }
    }
}

extern "C" void kernel_launch(void* const* d_in, const int* in_sizes, int n_in,
                              void* d_out, int out_size, void* d_ws, size_t ws_size,
                              hipStream_t stream)
{
    const float* attn_rgb = (const float*)d_in[0];
    const float* attn_tir = (const float*)d_in[1];
    const int*   gidx     = (const int*)  d_in[2];
    const float* ln_g     = (const float*)d_in[3];
    const float* ln_b     = (const float*)d_in[4];
    const float* W1       = (const float*)d_in[5];
    const float* b1       = (const float*)d_in[6];
    const float* W2       = (const float*)d_in[7];
    const float* b2       = (const float*)d_in[8];

    v4f* outTir = (v4f*)d_out;               // tir_col first per reference
    v4f* outRgb = outTir + (size_t)BH * SLICE4;

    k_fused<<<BH, 1024, 0, stream>>>(attn_rgb, attn_tir, gidx, ln_g, ln_b,
                                     W1, b1, W2, b2, outTir, outRgb);
}

// Round 15
// 149.098 us; speedup vs baseline: 1.3898x; 1.3898x over previous
//
#include <hip/hip_runtime.h>
#include <math.h>

// Problem constants
#define BB   32
#define HN   12
#define N1   256
#define N2   320
#define SS   256
#define BH   (BB*HN)                 // 384
#define R4   (N2/4)                  // 80 float4 per row
#define SLICE4 ((size_t)N1*R4)       // f4 per (b,h) per tensor = 20480

#define AGENT __HIP_MEMORY_SCOPE_AGENT
#define SENT  0xFFFFFFFFu            // NaN bit pattern: never a real max/sigmoid

typedef float v4f __attribute__((ext_vector_type(4)));

// 768 blocks x 256 threads = exactly 3 blocks/CU, all co-resident.
// Pair (bh, even)/(bh, odd): even owns rows 0-127, odd rows 128-255 (both
// tensors). Exchange is FENCE-FREE: workspace pre-set to NaN sentinel; the
// data itself is the flag (relaxed agent-scope atomics only -> no buffer_inv,
// L2/weights stay hot). Odd publishes its 256 row-maxes; even runs the single
// MLP per pair and publishes 256 pre-gathered gates; odd polls them.
__global__ __launch_bounds__(256, 3) void k_pair(
    const float* __restrict__ rgb, const float* __restrict__ tir,
    const int*   __restrict__ gidx,
    const float* __restrict__ ln_g, const float* __restrict__ ln_b,
    const float* __restrict__ W1,  const float* __restrict__ b1,
    const float* __restrict__ W2,  const float* __restrict__ b2,
    float* __restrict__ mx_g,     // [BH][256]  odd's maxes: tensor*128 + r'
    float* __restrict__ gate_g,   // [BH][256]  gates for odd: tensor*128 + r'
    v4f* __restrict__ outTir, v4f* __restrict__ outRgb)
{
    __shared__ float mxs_all[2][SS];  // [tensor][row] (even: full; odd: own)
    __shared__ float v[2 * SS];
    __shared__ float hs[SS];
    __shared__ float gs[2 * SS];
    __shared__ int   sidx_s[SS];
    __shared__ float red[8];
    __shared__ float growR[128];      // gates for own 128 rows
    __shared__ float growT[128];

    const int j    = (int)blockIdx.x;    // 0..767
    const int bh   = j >> 1;
    const int half = j & 1;              // 0: rows 0-127 (+MLP), 1: rows 128-255
    const int b    = bh / HN;
    const int t    = (int)threadIdx.x;   // 0..255
    const int w    = t >> 6;
    const int lane = t & 63;
    const int row0 = half * 128;

    const float* sliceR = rgb + (size_t)bh * (N1 * N2);
    const float* sliceT = tir + (size_t)bh * (N1 * N2);

    // ---- Phase A: rowmax of own 128 rows x 2 tensors (256 units, 8-deep) --
    for (int uu = 0; uu < 64; uu += 8) {
        const int u0 = w * 64 + uu;
        v4f a[8], b8[8];
#pragma unroll
        for (int q = 0; q < 8; ++q) {
            int u   = u0 + q;                    // 0..255: tensor*128 + r'
            int row = row0 + (u & 127);
            const v4f* p = (const v4f*)((u >= 128 ? sliceT : sliceR)
                                        + (size_t)row * N2);
            a[q]  = p[lane];
            // tail f4s [64,80): lane-duplicated (no effect on max; duplicate
            // addresses coalesce to the same cache lines)
            b8[q] = p[64 + (lane & 15)];
        }
#pragma unroll
        for (int q = 0; q < 8; ++q) {
            float m = fmaxf(fmaxf(fmaxf(a[q].x, a[q].y), fmaxf(a[q].z, a[q].w)),
                            fmaxf(fmaxf(b8[q].x, b8[q].y), fmaxf(b8[q].z, b8[q].w)));
#pragma unroll
            for (int off = 32; off; off >>= 1) m = fmaxf(m, __shfl_xor(m, off));
            if (lane == 0) {
                int u = u0 + q;
                mxs_all[u >> 7][row0 + (u & 127)] = m;
                if (half)   // publish to even sibling (data IS the flag)
                    __hip_atomic_store(&mx_g[bh * 256 + u], m,
                                       __ATOMIC_RELAXED, AGENT);
            }
        }
    }
    __syncthreads();

    if (half == 0) {
        // ---- poll sibling's maxes (one element per thread, no fences) ----
        {
            float val;
            for (;;) {
                val = __hip_atomic_load(&mx_g[bh * 256 + t],
                                        __ATOMIC_RELAXED, AGENT);
                if (__float_as_uint(val) != SENT) break;
                __builtin_amdgcn_s_sleep(1);
            }
            mxs_all[t >> 7][128 + (t & 127)] = val;
            sidx_s[t] = gidx[b * SS + t];
        }
        __syncthreads();

        // ---- scatter (per-batch permutation -> collision-free) ----
        {
            int sidx = sidx_s[t];
            v[sidx]      = mxs_all[0][t];
            v[sidx + SS] = mxs_all[1][t];
        }
        __syncthreads();

        {   // LayerNorm over 512
            float x0 = v[t], x1 = v[t + SS];
            float s  = x0 + x1;
            float sq = x0 * x0 + x1 * x1;
#pragma unroll
            for (int off = 32; off; off >>= 1) {
                s  += __shfl_xor(s, off);
                sq += __shfl_xor(sq, off);
            }
            if (lane == 0) { red[w] = s; red[4 + w] = sq; }
            __syncthreads();
            s  = red[0] + red[1] + red[2] + red[3];
            sq = red[4] + red[5] + red[6] + red[7];
            const float mu   = s * (1.f / 512.f);
            const float var  = sq * (1.f / 512.f) - mu * mu;
            const float rstd = rsqrtf(var + 1e-5f);
            v[t]      = (x0 - mu) * rstd * ln_g[t]      + ln_b[t];
            v[t + SS] = (x1 - mu) * rstd * ln_g[t + SS] + ln_b[t + SS];
        }
        __syncthreads();

        {   // GEMM1: hs[t] = relu(sum_e v[e]*W1[e*256+t] + b1[t])
            float a0 = b1[t], a1 = 0.f;
#pragma unroll 8
            for (int e = 0; e < SS; ++e)       a0 = fmaf(v[e], W1[e * SS + t], a0);
#pragma unroll 8
            for (int e = SS; e < 2 * SS; ++e)  a1 = fmaf(v[e], W1[e * SS + t], a1);
            hs[t] = fmaxf(a0 + a1, 0.f);
        }
        __syncthreads();

        {   // GEMM2: gs[t], gs[t+256] = sigmoid(sum_f hs[f]*W2[f*512+.] + b2)
            float lo0 = b2[t], lo1 = 0.f, hi0 = b2[t + SS], hi1 = 0.f;
#pragma unroll 8
            for (int f = 0; f < 128; ++f) {
                float hv = hs[f];
                lo0 = fmaf(hv, W2[f * 2 * SS + t],      lo0);
                hi0 = fmaf(hv, W2[f * 2 * SS + t + SS], hi0);
            }
#pragma unroll 8
            for (int f = 128; f < SS; ++f) {
                float hv = hs[f];
                lo1 = fmaf(hv, W2[f * 2 * SS + t],      lo1);
                hi1 = fmaf(hv, W2[f * 2 * SS + t + SS], hi1);
            }
            gs[t]      = 1.f / (1.f + expf(-(lo0 + lo1)));
            gs[t + SS] = 1.f / (1.f + expf(-(hi0 + hi1)));
        }
        __syncthreads();

        // own gates (rows 0-127) to LDS; sibling gates (rows 128-255) to ws
        if (t < 128) {
            int s = sidx_s[t];
            growR[t] = gs[s];
            growT[t] = gs[s + SS];
        }
        {
            int tensor = t >> 7, rp = t & 127;
            float gv = gs[sidx_s[128 + rp] + tensor * SS];
            __hip_atomic_store(&gate_g[bh * 256 + t], gv,
                               __ATOMIC_RELAXED, AGENT);
        }
        __syncthreads();
    } else {
        // ---- odd: poll pre-gathered gates (one element per thread) ----
        {
            float val;
            for (;;) {
                val = __hip_atomic_load(&gate_g[bh * 256 + t],
                                        __ATOMIC_RELAXED, AGENT);
                if (__float_as_uint(val) != SENT) break;
                __builtin_amdgcn_s_sleep(1);
            }
            if (t < 128) growR[t] = val;
            else         growT[t - 128] = val;
        }
        __syncthreads();
    }

    // ---- Phase C: modulate own rows [row0,row0+128), both tensors ----
    // Re-read is MALL-hot (FETCH pinned at ~250MB in R6/R10). NT stores.
    {
        const v4f* sR4 = (const v4f*)sliceR;
        const v4f* sT4 = (const v4f*)sliceT;
        v4f* dR = outRgb + (size_t)bh * SLICE4;
        v4f* dT = outTir + (size_t)bh * SLICE4;
        const unsigned base = (unsigned)row0 * 80u;          // f4 offset
        for (int k = 0; k < 80; k += 8) {                    // 20480 f4 flat
            v4f a[8]; float g[8];
#pragma unroll
            for (int q = 0; q < 8; ++q) {
                unsigned i  = (unsigned)(k + q) * 256u + (unsigned)t; // 0..20479
                int isRgb   = i >= 10240u;
                unsigned jj = isRgb ? i - 10240u : i;                 // 0..10239
                a[q] = (isRgb ? sR4 : sT4)[base + jj];
                g[q] = (isRgb ? growR : growT)[jj / 80u];
            }
#pragma unroll
            for (int q = 0; q < 8; ++q) {
                unsigned i  = (unsigned)(k + q) * 256u + (unsigned)t;
                int isRgb   = i >= 10240u;
                unsigned jj = isRgb ? i - 10240u : i;
                __builtin_nontemporal_store(a[q] * g[q],
                                            (isRgb ? dR : dT) + base + jj);
            }
        }
    }
}

extern "C" void kernel_launch(void* const* d_in, const int* in_sizes, int n_in,
                              void* d_out, int out_size, void* d_ws, size_t ws_size,
                              hipStream_t stream)
{
    const float* attn_rgb = (const float*)d_in[0];
    const float* attn_tir = (const float*)d_in[1];
    const int*   gidx     = (const int*)  d_in[2];
    const float* ln_g     = (const float*)d_in[3];
    const float* ln_b     = (const float*)d_in[4];
    const float* W1       = (const float*)d_in[5];
    const float* b1       = (const float*)d_in[6];
    const float* W2       = (const float*)d_in[7];
    const float* b2       = (const float*)d_in[8];

    // Workspace: mx_g [BH*256], gate_g [BH*256]; sentinel-filled each call.
    float* mx_g   = (float*)d_ws;
    float* gate_g = mx_g + (size_t)BH * 256;
    size_t sent_bytes = (size_t)BH * 256 * 4 * 2;            // 786,432 B

    v4f* outTir = (v4f*)d_out;               // tir_col first per reference
    v4f* outRgb = outTir + (size_t)BH * SLICE4;

    // NaN sentinel fill (graph-capture-safe async memset node).
    hipMemsetAsync(d_ws, 0xFF, sent_bytes, stream);

    k_pair<<<2 * BH, 256, 0, stream>>>(attn_rgb, attn_tir, gidx, ln_g, ln_b,
                                       W1, b1, W2, b2, mx_g, gate_g,
                                       outTir, outRgb);
}

// Round 16
// 147.447 us; speedup vs baseline: 1.4054x; 1.0112x over previous
//
#include <hip/hip_runtime.h>
#include <math.h>

// Problem constants
#define BB   32
#define HN   12
#define N1   256
#define N2   320
#define SS   256
#define BH   (BB*HN)                 // 384
#define R4   (N2/4)                  // 80 float4 per row
#define SLICE4 ((size_t)N1*R4)       // f4 per (b,h) per tensor = 20480

typedef float v4f __attribute__((ext_vector_type(4)));

// ---------- bf16 pack/unpack (RNE) ----------
__device__ __forceinline__ unsigned bf16rne(float x) {
    unsigned u = __float_as_uint(x);
    return (u + 0x7FFFu + ((u >> 16) & 1u)) >> 16;
}
__device__ __forceinline__ uint2 packbf(v4f a) {
    uint2 r;
    r.x = bf16rne(a.x) | (bf16rne(a.y) << 16);
    r.y = bf16rne(a.z) | (bf16rne(a.w) << 16);
    return r;
}
__device__ __forceinline__ v4f unpackbf(uint2 p) {
    v4f r;
    r.x = __uint_as_float(p.x << 16);
    r.y = __uint_as_float(p.x & 0xFFFF0000u);
    r.z = __uint_as_float(p.y << 16);
    r.w = __uint_as_float(p.y & 0xFFFF0000u);
    return r;
}

// ---------- phase-A batch helpers (inlined; arrays stay in regs) ----------
__device__ __forceinline__ void load_batch(
    const float* __restrict__ sliceR, const float* __restrict__ sliceT,
    int u0, int lane, v4f (&A)[8], v4f (&B)[8])
{
#pragma unroll
    for (int q = 0; q < 8; ++q) {
        int u = u0 + q;                       // tensor*256 + row
        const v4f* p = (const v4f*)((u >= SS ? sliceT : sliceR)
                                    + (size_t)(u & 255) * N2);
        A[q] = p[lane];
        // tail f4s [64,80): lane-duplicated (no effect on max; dup addresses
        // coalesce to the same cache lines)
        B[q] = p[64 + (lane & 15)];
    }
}
__device__ __forceinline__ void max_batch(
    int u0, int lane, const v4f (&A)[8], const v4f (&B)[8],
    float* __restrict__ mxs)
{
#pragma unroll
    for (int q = 0; q < 8; ++q) {
        float m = fmaxf(fmaxf(fmaxf(A[q].x, A[q].y), fmaxf(A[q].z, A[q].w)),
                        fmaxf(fmaxf(B[q].x, B[q].y), fmaxf(B[q].z, B[q].w)));
#pragma unroll
        for (int off = 32; off; off >>= 1) m = fmaxf(m, __shfl_xor(m, off));
        if (lane == 0) mxs[u0 + q] = m;
    }
}

// One block of 512 threads (8 waves) per (b,h). Zero inter-block sync.
//  Phase A: read own slice, 512 row-maxes; STASH 40% of the slice on-chip
//           as bf16 (16 main-f4/thread in regs + 64KB LDS) across the MLP.
//  Phase B: scatter -> LN(512) -> GEMM1(relu) -> GEMM2(sigmoid)  (R10 form).
//  Phase C: stashed part: unpack*gate, NT-store (no loads); rest re-read
//           (L3-hot), scale, NT-store.
__global__ __launch_bounds__(512, 4) void k_fused(
    const float* __restrict__ rgb, const float* __restrict__ tir,
    const int*   __restrict__ gidx,
    const float* __restrict__ ln_g, const float* __restrict__ ln_b,
    const float* __restrict__ W1,  const float* __restrict__ b1,
    const float* __restrict__ W2,  const float* __restrict__ b2,
    v4f* __restrict__ outTir, v4f* __restrict__ outRgb)
{
    __shared__ uint2 lstash[8][16][64];  // 64 KB bf16 stash: [wave][unit][lane]
    __shared__ float mxs[2 * SS];        // row maxes: rgb [0,256), tir [256,512)
    __shared__ float v[2 * SS];          // scattered -> normalized vector
    __shared__ float h2[2][SS];          // GEMM1 segment partials
    __shared__ float hs[SS];             // hidden relu
    __shared__ float gs[2 * SS];         // sigmoid gates
    __shared__ float growR[SS];          // per-row gate, rgb
    __shared__ float growT[SS];          // per-row gate, tir
    __shared__ int   sidx_s[SS];
    __shared__ float red[16];

    const int bh   = (int)blockIdx.x;    // 0..383
    const int b    = bh / HN;
    const int t    = (int)threadIdx.x;   // 0..511
    const int w    = t >> 6;             // wave 0..7
    const int lane = t & 63;

    if (t < SS) sidx_s[t] = gidx[b * SS + t];
    v[t] = 0.f;

    const float* sliceR = rgb + (size_t)bh * (N1 * N2);
    const float* sliceT = tir + (size_t)bh * (N1 * N2);

    // ---- Phase A: 512 row-units; wave w owns [w*64, w*64+64) ----
    uint2 rs[16];                        // register stash: units +0..15 (bf16)
    {
        v4f a[8], bb[8];
        load_batch(sliceR, sliceT, w * 64 + 0, lane, a, bb);
        max_batch(w * 64 + 0, lane, a, bb, mxs);
#pragma unroll
        for (int q = 0; q < 8; ++q) rs[q] = packbf(a[q]);
    }
    {
        v4f a[8], bb[8];
        load_batch(sliceR, sliceT, w * 64 + 8, lane, a, bb);
        max_batch(w * 64 + 8, lane, a, bb, mxs);
#pragma unroll
        for (int q = 0; q < 8; ++q) rs[8 + q] = packbf(a[q]);
    }
    {
        v4f a[8], bb[8];
        load_batch(sliceR, sliceT, w * 64 + 16, lane, a, bb);
        max_batch(w * 64 + 16, lane, a, bb, mxs);
#pragma unroll
        for (int q = 0; q < 8; ++q) lstash[w][q][lane] = packbf(a[q]);
    }
    {
        v4f a[8], bb[8];
        load_batch(sliceR, sliceT, w * 64 + 24, lane, a, bb);
        max_batch(w * 64 + 24, lane, a, bb, mxs);
#pragma unroll
        for (int q = 0; q < 8; ++q) lstash[w][8 + q][lane] = packbf(a[q]);
    }
    for (int uu = 32; uu < 64; uu += 8) {
        v4f a[8], bb[8];
        load_batch(sliceR, sliceT, w * 64 + uu, lane, a, bb);
        max_batch(w * 64 + uu, lane, a, bb, mxs);
    }
    __syncthreads();

    // ---- Phase B1: scatter (per-batch permutation -> collision-free) ----
    if (t < SS) {
        int sidx = sidx_s[t];
        v[sidx]      = mxs[t];
        v[sidx + SS] = mxs[t + SS];
    }
    __syncthreads();

    // ---- Phase B2: LayerNorm over 512 (one element per thread) ----
    {
        float x  = v[t];
        float s  = x;
        float sq = x * x;
#pragma unroll
        for (int off = 32; off; off >>= 1) {
            s  += __shfl_xor(s, off);
            sq += __shfl_xor(sq, off);
        }
        if (lane == 0) { red[w] = s; red[8 + w] = sq; }
        __syncthreads();
        s  = red[0] + red[1] + red[2] + red[3] + red[4] + red[5] + red[6] + red[7];
        sq = red[8] + red[9] + red[10] + red[11] + red[12] + red[13] + red[14] + red[15];
        const float mu   = s * (1.f / 512.f);
        const float var  = sq * (1.f / 512.f) - mu * mu;
        const float rstd = rsqrtf(var + 1e-5f);
        v[t] = (x - mu) * rstd * ln_g[t] + ln_b[t];
    }
    __syncthreads();

    // ---- Phase B3: GEMM1 partials. out = t&255, seg = t>>8 (256 e each) ---
    {
        const int out = t & 255, seg = t >> 8;
        const int e0  = seg * SS;
        float a0 = (seg == 0) ? b1[out] : 0.f, a1 = 0.f;
#pragma unroll 8
        for (int e = 0; e < 128; ++e)
            a0 = fmaf(v[e0 + e], W1[(size_t)(e0 + e) * SS + out], a0);
#pragma unroll 8
        for (int e = 128; e < 256; ++e)
            a1 = fmaf(v[e0 + e], W1[(size_t)(e0 + e) * SS + out], a1);
        h2[seg][out] = a0 + a1;
    }
    __syncthreads();
    if (t < SS) hs[t] = fmaxf(h2[0][t] + h2[1][t], 0.f);
    __syncthreads();

    // ---- Phase B4: GEMM2, one output per thread (512 outputs) ----
    {
        float a0 = b2[t], a1 = 0.f;
#pragma unroll 8
        for (int f = 0; f < 128; ++f)      a0 = fmaf(hs[f], W2[(size_t)f * (2 * SS) + t], a0);
#pragma unroll 8
        for (int f = 128; f < 256; ++f)    a1 = fmaf(hs[f], W2[(size_t)f * (2 * SS) + t], a1);
        gs[t] = 1.f / (1.f + expf(-(a0 + a1)));
    }
    __syncthreads();

    // ---- Phase B5: gather per-row gates ----
    if (t < SS) {
        growR[t] = gs[sidx_s[t]];
        growT[t] = gs[sidx_s[t] + SS];
    }
    __syncthreads();

    // ---- Phase C: row-mapped modulate; stash covers units +0..31 mains ----
    {
        const v4f* sR4 = (const v4f*)sliceR;
        const v4f* sT4 = (const v4f*)sliceT;
        v4f* dR = outRgb + (size_t)bh * SLICE4;
        v4f* dT = outTir + (size_t)bh * SLICE4;

        // (3) re-read mains, units +32..63 (L3-hot), 8-deep batches
        for (int uu = 32; uu < 64; uu += 8) {
            v4f a[8];
#pragma unroll
            for (int q = 0; q < 8; ++q) {
                int u = w * 64 + uu + q;
                a[q] = (u >= SS ? sT4 : sR4)[(size_t)(u & 255) * R4 + lane];
            }
#pragma unroll
            for (int q = 0; q < 8; ++q) {
                int u   = w * 64 + uu + q;
                int row = u & 255;
                float g = (u >= SS ? growT : growR)[row];
                v4f*  d = (u >= SS ? dT : dR) + (size_t)row * R4;
                __builtin_nontemporal_store(a[q] * g, d + lane);
            }
        }
        // (4) tails [64,80) for ALL 64 units (lanes 0..15), 8-deep batches
        for (int uu = 0; uu < 64; uu += 8) {
            if (lane < 16) {
                v4f tl[8];
#pragma unroll
                for (int q = 0; q < 8; ++q) {
                    int u = w * 64 + uu + q;
                    tl[q] = (u >= SS ? sT4 : sR4)[(size_t)(u & 255) * R4 + 64 + lane];
                }
#pragma unroll
                for (int q = 0; q < 8; ++q) {
                    int u   = w * 64 + uu + q;
                    int row = u & 255;
                    float g = (u >= SS ? growT : growR)[row];
                    v4f*  d = (u >= SS ? dT : dR) + (size_t)row * R4;
                    __builtin_nontemporal_store(tl[q] * g, d + 64 + lane);
                }
            }
        }
        // (1) register-stashed mains, units +0..15 (no loads)
#pragma unroll
        for (int q = 0; q < 16; ++q) {
            int u   = w * 64 + q;
            int row = u & 255;
            float g = (u >= SS ? growT : growR)[row];
            v4f*  d = (u >= SS ? dT : dR) + (size_t)row * R4;
            __builtin_nontemporal_store(unpackbf(rs[q]) * g, d + lane);
        }
        // (2) LDS-stashed mains, units +16..31 (ds_read_b64, conflict-free)
#pragma unroll
        for (int q = 0; q < 16; ++q) {
            int u   = w * 64 + 16 + q;
            int row = u & 255;
            float g = (u >= SS ? growT : growR)[row];
            v4f*  d = (u >= SS ? dT : dR) + (size_t)row * R4;
            __builtin_nontemporal_store(unpackbf(lstash[w][q][lane]) * g, d + lane);
        }
    }
}

extern "C" void kernel_launch(void* const* d_in, const int* in_sizes, int n_in,
                              void* d_out, int out_size, void* d_ws, size_t ws_size,
                              hipStream_t stream)
{
    const float* attn_rgb = (const float*)d_in[0];
    const float* attn_tir = (const float*)d_in[1];
    const int*   gidx     = (const int*)  d_in[2];
    const float* ln_g     = (const float*)d_in[3];
    const float* ln_b     = (const float*)d_in[4];
    const float* W1       = (const float*)d_in[5];
    const float* b1       = (const float*)d_in[6];
    const float* W2       = (const float*)d_in[7];
    const float* b2       = (const float*)d_in[8];

    v4f* outTir = (v4f*)d_out;               // tir_col first per reference
    v4f* outRgb = outTir + (size_t)BH * SLICE4;

    k_fused<<<BH, 512, 0, stream>>>(attn_rgb, attn_tir, gidx, ln_g, ln_b,
                                    W1, b1, W2, b2, outTir, outRgb);
}

// Round 17
// 133.098 us; speedup vs baseline: 1.5569x; 1.1078x over previous
//
#include <hip/hip_runtime.h>
#include <hip/hip_bf16.h>
#include <math.h>

// Problem constants
#define BB   32
#define HN   12
#define N1   256
#define N2   320
#define SS   256
#define BH   (BB*HN)                 // 384
#define R4   (N2/4)                  // 80 float4 per row
#define SLICE4 ((size_t)N1*R4)       // f4 per (b,h) per tensor = 20480

typedef float v4f __attribute__((ext_vector_type(4)));

// CHAMPION (R10 structure, measured 134.3 us):
// One block of 512 threads (8 waves) per (b,h). No inter-block sync, no
// barriers beyond __syncthreads, no workspace. launch_bounds(512,4):
// 4 waves/SIMD -> 2 blocks/CU, VGPR cap 128.
//  Phase A: read own slice once, 512 row-maxes -> LDS (8-deep load batches).
//  Phase B: scatter -> LN(512) -> GEMM1(relu) -> GEMM2(sigmoid), all waves.
//  Phase C: re-read own slice (~1us old -> MALL/L2-hot), scale, NT-store
//           (NT stores don't allocate in L3 -> inputs stay resident;
//            FETCH_SIZE pinned at ~250MB across R6/R10 = single-fetch).
__global__ __launch_bounds__(512, 4) void k_fused(
    const float* __restrict__ rgb, const float* __restrict__ tir,
    const int*   __restrict__ gidx,
    const float* __restrict__ ln_g, const float* __restrict__ ln_b,
    const float* __restrict__ W1,  const float* __restrict__ b1,
    const float* __restrict__ W2,  const float* __restrict__ b2,
    v4f* __restrict__ outTir, v4f* __restrict__ outRgb)
{
    __shared__ float mxs[2 * SS];    // row maxes: rgb [0,256), tir [256,512)
    __shared__ float v[2 * SS];      // scattered -> normalized vector
    __shared__ float h2[2][SS];      // GEMM1 segment partials
    __shared__ float hs[SS];         // hidden relu
    __shared__ float gs[2 * SS];     // sigmoid gates
    __shared__ float growR[SS];      // per-row gate, rgb
    __shared__ float growT[SS];      // per-row gate, tir
    __shared__ int   sidx_s[SS];
    __shared__ float red[16];

    const int bh   = (int)blockIdx.x;    // 0..383
    const int b    = bh / HN;
    const int t    = (int)threadIdx.x;   // 0..511
    const int w    = t >> 6;             // wave 0..7
    const int lane = t & 63;

    if (t < SS) sidx_s[t] = gidx[b * SS + t];
    v[t] = 0.f;

    const float* sliceR = rgb + (size_t)bh * SLICE4 * 4;
    const float* sliceT = tir + (size_t)bh * SLICE4 * 4;

    // ---- Phase A: row maxes. 512 row-units (tensor,row); 64 per wave,
    // 8-unit load batches (16 independent loads in flight). Tail f4s [64,80)
    // loaded unconditionally via (lane&15) duplication: duplicate lanes can't
    // change a max and coalesce to the same cache lines.
    for (int uu = 0; uu < 64; uu += 8) {
        const int u0 = w * 64 + uu;
        v4f a[8], b8[8];
#pragma unroll
        for (int q = 0; q < 8; ++q) {
            int u   = u0 + q;
            int row = u & 255;
            const v4f* p = (const v4f*)((u >= SS ? sliceT : sliceR)
                                        + (size_t)row * N2);
            a[q]  = p[lane];
            b8[q] = p[64 + (lane & 15)];
        }
#pragma unroll
        for (int q = 0; q < 8; ++q) {
            float m = fmaxf(fmaxf(fmaxf(a[q].x, a[q].y), fmaxf(a[q].z, a[q].w)),
                            fmaxf(fmaxf(b8[q].x, b8[q].y), fmaxf(b8[q].z, b8[q].w)));
#pragma unroll
            for (int off = 32; off; off >>= 1) m = fmaxf(m, __shfl_xor(m, off));
            if (lane == 0) mxs[u0 + q] = m;
        }
    }
    __syncthreads();

    // ---- Phase B1: scatter (per-batch permutation -> collision-free) ----
    if (t < SS) {
        int sidx = sidx_s[t];
        v[sidx]      = mxs[t];
        v[sidx + SS] = mxs[t + SS];
    }
    __syncthreads();

    // ---- Phase B2: LayerNorm over 512 (one element per thread) ----
    {
        float x  = v[t];
        float s  = x;
        float sq = x * x;
#pragma unroll
        for (int off = 32; off; off >>= 1) {
            s  += __shfl_xor(s, off);
            sq += __shfl_xor(sq, off);
        }
        if (lane == 0) { red[w] = s; red[8 + w] = sq; }
        __syncthreads();
        s  = red[0] + red[1] + red[2] + red[3] + red[4] + red[5] + red[6] + red[7];
        sq = red[8] + red[9] + red[10] + red[11] + red[12] + red[13] + red[14] + red[15];
        const float mu   = s * (1.f / 512.f);
        const float var  = sq * (1.f / 512.f) - mu * mu;
        const float rstd = rsqrtf(var + 1e-5f);
        v[t] = (x - mu) * rstd * ln_g[t] + ln_b[t];
    }
    __syncthreads();

    // ---- Phase B3: GEMM1 partials. out = t&255, seg = t>>8 (256 e each) ---
    {
        const int out = t & 255, seg = t >> 8;
        const int e0  = seg * SS;
        float a0 = (seg == 0) ? b1[out] : 0.f, a1 = 0.f;
#pragma unroll 8
        for (int e = 0; e < 128; ++e)
            a0 = fmaf(v[e0 + e], W1[(size_t)(e0 + e) * SS + out], a0);
#pragma unroll 8
        for (int e = 128; e < 256; ++e)
            a1 = fmaf(v[e0 + e], W1[(size_t)(e0 + e) * SS + out], a1);
        h2[seg][out] = a0 + a1;
    }
    __syncthreads();
    if (t < SS) hs[t] = fmaxf(h2[0][t] + h2[1][t], 0.f);
    __syncthreads();

    // ---- Phase B4: GEMM2, one output per thread (512 outputs) ----
    {
        float a0 = b2[t], a1 = 0.f;
#pragma unroll 8
        for (int f = 0; f < 128; ++f)      a0 = fmaf(hs[f], W2[(size_t)f * (2 * SS) + t], a0);
#pragma unroll 8
        for (int f = 128; f < 256; ++f)    a1 = fmaf(hs[f], W2[(size_t)f * (2 * SS) + t], a1);
        gs[t] = 1.f / (1.f + expf(-(a0 + a1)));
    }
    __syncthreads();

    // ---- Phase B5: gather per-row gates ----
    if (t < SS) {
        growR[t] = gs[sidx_s[t]];
        growT[t] = gs[sidx_s[t] + SS];
    }
    __syncthreads();

    // ---- Phase C: hot re-read own slice, scale, NT-store ----
    // 40960 f4 (both tensors), flat: i = k*512 + t; tir first half.
    {
        const v4f* srcR4 = (const v4f*)sliceR;
        const v4f* srcT4 = (const v4f*)sliceT;
        v4f* dstR = outRgb + (size_t)bh * SLICE4;
        v4f* dstT = outTir + (size_t)bh * SLICE4;
        for (int k = 0; k < 80; k += 8) {
            v4f a[8]; float g[8];
#pragma unroll
            for (int q = 0; q < 8; ++q) {
                unsigned i = (unsigned)(k + q) * 512u + (unsigned)t;  // < 40960
                int isRgb  = i >= 20480u;
                unsigned j = isRgb ? i - 20480u : i;
                a[q] = isRgb ? srcR4[j] : srcT4[j];
                g[q] = (isRgb ? growR : growT)[j / 80u];
            }
#pragma unroll
            for (int q = 0; q < 8; ++q) {
                unsigned i = (unsigned)(k + q) * 512u + (unsigned)t;
                int isRgb  = i >= 20480u;
                unsigned j = isRgb ? i - 20480u : i;
                __builtin_nontemporal_store(a[q] * g[q],
                                            (isRgb ? dstR : dstT) + j);
            }
        }
    }
}

extern "C" void kernel_launch(void* const* d_in, const int* in_sizes, int n_in,
                              void* d_out, int out_size, void* d_ws, size_t ws_size,
                              hipStream_t stream)
{
    const float* attn_rgb = (const float*)d_in[0];
    const float* attn_tir = (const float*)d_in[1];
    const int*   gidx     = (const int*)  d_in[2];
    const float* ln_g     = (const float*)d_in[3];
    const float* ln_b     = (const float*)d_in[4];
    const float* W1       = (const float*)d_in[5];
    const float* b1       = (const float*)d_in[6];
    const float* W2       = (const float*)d_in[7];
    const float* b2       = (const float*)d_in[8];

    v4f* outTir = (v4f*)d_out;               // tir_col first per reference
    v4f* outRgb = outTir + (size_t)BH * SLICE4;

    k_fused<<<BH, 512, 0, stream>>>(attn_rgb, attn_tir, gidx, ln_g, ln_b,
                                    W1, b1, W2, b2, outTir, outRgb);
}